// Round 15
// baseline (887.795 us; speedup 1.0000x reference)
//
#include <hip/hip_runtime.h>
#include <hip/hip_bf16.h>

#define NN 100000
#define EE 1600000
#define ETOT (NN + EE)
#define HID 128
#define HEADS 8
#define CH 16
#define EPS_BN 1e-5f
#define NEG_SLOPE 0.2f
#define LOG2E 1.4426950408889634f
#define NB 196            // buckets of 512 dst nodes
#define NBLK_A 208        // ceil(ETOT / 8192)
#define SREP 64           // stat replicas (contention: ~390 adds/address)

typedef unsigned short ushort_t;
typedef unsigned int uint_t;
typedef __attribute__((ext_vector_type(8))) short short8;
typedef __attribute__((ext_vector_type(4))) float float4v;

__device__ inline uint_t f2bf(float x) {
    __hip_bfloat16 b = __float2bfloat16(x);
    return (uint_t)*reinterpret_cast<unsigned short*>(&b);
}
__device__ inline uint_t pack2(float lo, float hi) {
    return f2bf(lo) | (f2bf(hi) << 16);
}
__device__ inline float bf_lo(uint_t u) { return __uint_as_float(u << 16); }
__device__ inline float bf_hi(uint_t u) { return __uint_as_float(u & 0xffff0000u); }

// async global->LDS, 16B per lane; LDS dest must be wave-uniform base + lane*16
__device__ inline void gld_lds16(const void* g, void* l) {
    __builtin_amdgcn_global_load_lds(
        (const __attribute__((address_space(1))) unsigned int*)g,
        (__attribute__((address_space(3))) unsigned int*)l, 16, 0, 0);
}

// ================= CSR build: bucketed counting sort =================

__global__ __launch_bounds__(256) void bucket_hist(const int* __restrict__ ei,
                                                   int* bcnt, int* lbase) {
    __shared__ int h[256];
    int t = threadIdx.x;
    h[t] = 0;
    __syncthreads();
    int base = blockIdx.x * 8192;
    #pragma unroll 4
    for (int j = 0; j < 32; ++j) {
        int i = base + j * 256 + t;
        if (i < ETOT) {
            int d = (i < EE) ? ei[EE + i] : (i - EE);
            atomicAdd(&h[d >> 9], 1);
        }
    }
    __syncthreads();
    // guard t < NB: lbase stride is NB (round-4 crash root cause)
    if (t < NB) {
        int v = h[t];
        lbase[blockIdx.x * NB + t] = v ? atomicAdd(&bcnt[t], v) : 0;
    }
}

__global__ void bucket_scan(const int* __restrict__ bcnt, int* bbase, int* rowptr) {
    __shared__ int s[256];
    int t = threadIdx.x;
    int orig = (t < NB) ? bcnt[t] : 0;
    s[t] = orig;
    __syncthreads();
    for (int off = 1; off < 256; off <<= 1) {
        int add = (t >= off) ? s[t - off] : 0;
        __syncthreads();
        s[t] += add;
        __syncthreads();
    }
    if (t < NB) bbase[t] = s[t] - orig;
    if (t == 0) { bbase[NB] = ETOT; rowptr[NN] = ETOT; }
}

// LDS-staged counting sort per block; linear coalesced write.
__global__ __launch_bounds__(256) void bucket_scatter(const int* __restrict__ ei,
                                                      const int* __restrict__ bbase,
                                                      const int* __restrict__ lbase,
                                                      uint_t* __restrict__ pairs) {
    __shared__ uint_t spair[8192];
    __shared__ unsigned char sbk[8192];
    __shared__ int h[256];
    __shared__ int lscan[256];
    __shared__ int sbase[256];
    int t = threadIdx.x;
    int base = blockIdx.x * 8192;
    int nloc = ETOT - base; if (nloc > 8192) nloc = 8192;
    sbase[t] = (t < NB) ? (bbase[t] + lbase[blockIdx.x * NB + t]) : 0;
    h[t] = 0;
    __syncthreads();
    #pragma unroll 4
    for (int j = 0; j < 32; ++j) {
        int i = base + j * 256 + t;
        if (i < ETOT) {
            int d = (i < EE) ? ei[EE + i] : (i - EE);
            atomicAdd(&h[d >> 9], 1);
        }
    }
    __syncthreads();
    int orig = h[t];
    lscan[t] = orig;
    __syncthreads();
    for (int off = 1; off < 256; off <<= 1) {
        int add = (t >= off) ? lscan[t - off] : 0;
        __syncthreads();
        lscan[t] += add;
        __syncthreads();
    }
    int excl = lscan[t] - orig;
    __syncthreads();
    lscan[t] = excl;
    h[t] = excl;
    __syncthreads();
    #pragma unroll 4
    for (int j = 0; j < 32; ++j) {
        int i = base + j * 256 + t;
        if (i < ETOT) {
            int sv, dv;
            if (i < EE) { sv = ei[i]; dv = ei[EE + i]; }
            else        { sv = i - EE; dv = sv; }
            int bk = dv >> 9;
            int lp = atomicAdd(&h[bk], 1);
            spair[lp] = ((uint_t)sv << 9) | (uint_t)(dv & 511);
            sbk[lp] = (unsigned char)bk;
        }
    }
    __syncthreads();
    #pragma unroll 4
    for (int j = 0; j < 32; ++j) {
        int i = j * 256 + t;
        if (i < nloc) {
            int bk = sbk[i];
            pairs[sbase[bk] + (i - lscan[bk])] = spair[i];
        }
    }
}

__global__ __launch_bounds__(256) void bucket_build(const uint_t* __restrict__ pairs,
                                                    const int* __restrict__ bbase,
                                                    int* __restrict__ rowptr,
                                                    int* __restrict__ csrc) {
    __shared__ int cnt[512];
    __shared__ int cur[512];
    int b = blockIdx.x;
    int t = threadIdx.x;
    int lo = b << 9;
    int nn = NN - lo; if (nn > 512) nn = 512;
    int e0 = bbase[b];
    int e1 = bbase[b + 1];
    cnt[t] = 0; cnt[t + 256] = 0;
    __syncthreads();
    for (int i = e0 + t; i < e1; i += 256)
        atomicAdd(&cnt[pairs[i] & 511], 1);
    __syncthreads();
    int oc0 = cnt[t], oc1 = cnt[t + 256];
    for (int off = 1; off < 512; off <<= 1) {
        int i0 = t, i1 = t + 256;
        int a0 = cnt[i0] + ((i0 >= off) ? cnt[i0 - off] : 0);
        int a1 = cnt[i1] + ((i1 >= off) ? cnt[i1 - off] : 0);
        __syncthreads();
        cnt[i0] = a0; cnt[i1] = a1;
        __syncthreads();
    }
    int ex0 = cnt[t] - oc0, ex1 = cnt[t + 256] - oc1;
    __syncthreads();
    cur[t] = e0 + ex0; cur[t + 256] = e0 + ex1;
    if (t < nn)       rowptr[lo + t] = e0 + ex0;
    if (t + 256 < nn) rowptr[lo + 256 + t] = e0 + ex1;
    __syncthreads();
    for (int i = e0 + t; i < e1; i += 256) {
        uint_t p = pairs[i];
        int pos = atomicAdd(&cur[p & 511], 1);
        csrc[pos] = (int)(p >> 9);
    }
}

// ================= weight transpose + cast (+ zero bcnt/srep) =================

__global__ void castw(const float* __restrict__ proj_w, const float* __restrict__ W,
                      ushort_t* __restrict__ pwT, ushort_t* __restrict__ WT,
                      int* __restrict__ bcnt, float* __restrict__ srep) {
    int id = blockIdx.x * 256 + threadIdx.x;
    if (id < 256) bcnt[id] = 0;
    if (id < 3 * SREP * 256) srep[id] = 0.f;               // 49152 stat partials
    if (id < 32768) {
        int n = id >> 8, k = id & 255;
        pwT[id] = (ushort_t)f2bf(proj_w[k * 128 + n]);     // pwT[n][k], K=256
    } else if (id < 81920) {
        int id2 = id - 32768;
        int l = id2 >> 14, r = id2 & 16383;
        int n = r >> 7, k = r & 127;
        WT[id2] = (ushort_t)f2bf(W[l * 16384 + k * 128 + n]); // WT[l][n][k]
    }
}

// ================= proj GEMM (K=256, fp32 A): 512-thread frag-staged ==========

__global__ __launch_bounds__(512) void proj_gemm(
    const float* __restrict__ A, const ushort_t* __restrict__ Bt,
    const float* __restrict__ bias, ushort_t* __restrict__ Cb)
{
    __shared__ uint4 smem[4096];                 // 64 KB: A frags | B frags
    ushort_t* As = (ushort_t*)smem;              // 32 KB (one K=128 half)
    ushort_t* Bs = As + 16384;                   // 32 KB

    int t = threadIdx.x;
    int row0 = blockIdx.x * 128;
    int lane = t & 63, wv = t >> 6;              // 8 waves
    int wm = wv >> 1, wn = wv & 1;               // wm in [0,4), wn in [0,2)
    int lr = lane & 15, quad = lane >> 4;

    float4v acc[2][4] = {};

    for (int h = 0; h < 2; ++h) {
        #pragma unroll
        for (int j = 0; j < 4; ++j) {
            int idx = j * 512 + t;
            int tile = idx >> 8, ksf = (idx >> 6) & 3;
            int l = idx & 63;
            int n = tile * 16 + (l & 15);
            int kk = h * 128 + ksf * 32 + (l >> 4) * 8;
            gld_lds16(Bt + n * 256 + kk, Bs + (size_t)idx * 8);
        }
        #pragma unroll
        for (int j = 0; j < 4; ++j) {
            int idx = j * 512 + t;
            int tile = idx >> 8, ksf = (idx >> 6) & 3;
            int l = idx & 63;
            int row = row0 + tile * 16 + (l & 15);
            if (row >= NN) row = NN - 1;         // clamp: no OOB on input x
            int kk = h * 128 + ksf * 32 + (l >> 4) * 8;
            const float* src = A + (size_t)row * 256 + kk;
            float4 v0 = *(const float4*)(src);
            float4 v1 = *(const float4*)(src + 4);
            uint4 o;
            o.x = pack2(v0.x, v0.y); o.y = pack2(v0.z, v0.w);
            o.z = pack2(v1.x, v1.y); o.w = pack2(v1.z, v1.w);
            *(uint4*)(As + (size_t)idx * 8) = o;
        }
        __syncthreads();                         // drains DMA + ds_writes

        #pragma unroll
        for (int ks = 0; ks < 4; ++ks) {
            short8 a[2], b[4];
            #pragma unroll
            for (int tj = 0; tj < 4; ++tj)
                b[tj] = *(const short8*)(Bs + ((wn * 4 + tj) * 4 + ks) * 512 + lane * 8);
            #pragma unroll
            for (int ti = 0; ti < 2; ++ti)
                a[ti] = *(const short8*)(As + ((wm * 2 + ti) * 4 + ks) * 512 + lane * 8);
            #pragma unroll
            for (int ti = 0; ti < 2; ++ti)
                #pragma unroll
                for (int tj = 0; tj < 4; ++tj)
                    acc[ti][tj] = __builtin_amdgcn_mfma_f32_16x16x32_bf16(
                        a[ti], b[tj], acc[ti][tj], 0, 0, 0);
        }
        __syncthreads();                         // protect LDS before restage/bounce
    }

    float* sc = (float*)smem;
    for (int tp = 0; tp < 2; ++tp) {
        if ((wm >> 1) == tp) {
            #pragma unroll
            for (int ti = 0; ti < 2; ++ti) {
                #pragma unroll
                for (int tj = 0; tj < 4; ++tj) {
                    #pragma unroll
                    for (int r = 0; r < 4; ++r) {
                        int rloc = (wm & 1) * 32 + ti * 16 + quad * 4 + r;
                        int col = wn * 64 + tj * 16 + lr;
                        sc[rloc * 132 + col] = acc[ti][tj][r];
                    }
                }
            }
        }
        __syncthreads();
        #pragma unroll
        for (int j = 0; j < 4; ++j) {
            int idx = j * 512 + t;
            int row = idx >> 5;                 // [0,64)
            int c4 = (idx & 31) * 4;
            float4 v = *(const float4*)&sc[row * 132 + c4];
            int gr = row0 + tp * 64 + row;
            if (gr < NN) {
                float4 bv = *(const float4*)(bias + c4);
                v.x += bv.x; v.y += bv.y; v.z += bv.z; v.w += bv.w;
                v.x = v.x > 0.f ? v.x : __expf(v.x) - 1.f;
                v.y = v.y > 0.f ? v.y : __expf(v.y) - 1.f;
                v.z = v.z > 0.f ? v.z : __expf(v.z) - 1.f;
                v.w = v.w > 0.f ? v.w : __expf(v.w) - 1.f;
                uint2 u; u.x = pack2(v.x, v.y); u.y = pack2(v.z, v.w);
                *(uint2*)(Cb + (size_t)gr * 128 + c4) = u;
            }
        }
        __syncthreads();
    }
}

// ================= layer GEMM (K=128, N=128): 512-thread / 8-wave version =====
// mode 2 consumes srep (SREP x 256 stat partials from fused gat_agg).

__global__ __launch_bounds__(512) void layer_gemm(
    const void* __restrict__ Aptr, int mode,
    const ushort_t* __restrict__ Bt, ushort_t* __restrict__ Cb,
    const float* __restrict__ a_src, const float* __restrict__ a_dst,
    float* __restrict__ al_s, float* __restrict__ al_d,
    uint_t* __restrict__ hbio, const float* __restrict__ srep,
    const float* __restrict__ bn_gl, const float* __restrict__ bn_bl)
{
    __shared__ uint4 smem[4096];                 // 64 KB: A frags | B frags
    __shared__ float2 scsh[128];
    ushort_t* As = (ushort_t*)smem;              // 2048 frags * 16 B
    ushort_t* Bs = As + 16384;

    int t = threadIdx.x;
    int row0 = blockIdx.x * 128;
    int lane = t & 63, wv = t >> 6;              // 8 waves
    int wm = wv >> 1, wn = wv & 1;               // wm in [0,4), wn in [0,2)
    int lr = lane & 15, quad = lane >> 4;

    if (mode == 2) {
        if (t < 128) {
            float s_ = 0.f, q_ = 0.f;
            #pragma unroll 8
            for (int r = 0; r < SREP; ++r) {
                s_ += srep[r * 256 + t];
                q_ += srep[r * 256 + 128 + t];
            }
            float mu = s_ * (1.0f / NN);
            float var = q_ * (1.0f / NN) - mu * mu;
            float s = bn_gl[t] * rsqrtf(var + EPS_BN);
            scsh[t] = make_float2(s, bn_bl[t] - mu * s);
        }
        __syncthreads();                         // scsh visible before transforms
    }

    #pragma unroll
    for (int j = 0; j < 4; ++j) {
        int idx = j * 512 + t;
        int tile = idx >> 8, ksf = (idx >> 6) & 3;
        int l = idx & 63;
        int n = tile * 16 + (l & 15);
        int kk = ksf * 32 + (l >> 4) * 8;
        gld_lds16(Bt + n * 128 + kk, Bs + (size_t)idx * 8);
    }

    if (mode == 0) {
        const ushort_t* A = (const ushort_t*)Aptr;
        #pragma unroll
        for (int j = 0; j < 4; ++j) {
            int idx = j * 512 + t;
            int tile = idx >> 8, ksf = (idx >> 6) & 3;
            int l = idx & 63;
            int row = row0 + tile * 16 + (l & 15);   // OOB rows read garbage -> dead C rows only
            int kk = ksf * 32 + (l >> 4) * 8;
            gld_lds16(A + (size_t)row * 128 + kk, As + (size_t)idx * 8);
        }
    } else {
        const uint_t* agg = (const uint_t*)Aptr;
        uint4 av[4], rv[4];
        unsigned gi[4];
        int rowv[4];
        #pragma unroll
        for (int j = 0; j < 4; ++j) {
            int idx = j * 512 + t;
            int tile = idx >> 8;
            int ksf = (idx >> 6) & 3;
            int l = idx & 63;
            int row = row0 + tile * 16 + (l & 15);
            int kk = ksf * 32 + (l >> 4) * 8;
            unsigned ui = (unsigned)row * 64u + (unsigned)(kk >> 1);
            gi[j] = ui; rowv[j] = row;
            av[j] = *(const uint4*)(agg + ui);
            rv[j] = *(const uint4*)(hbio + ui);
        }
        #pragma unroll
        for (int j = 0; j < 4; ++j) {
            int idx = j * 512 + t;
            int ksf = (idx >> 6) & 3;
            int l = idx & 63;
            int kk = ksf * 32 + (l >> 4) * 8;        // channel base, 8 channels
            uint_t aa[4] = {av[j].x, av[j].y, av[j].z, av[j].w};
            uint_t rr[4] = {rv[j].x, rv[j].y, rv[j].z, rv[j].w};
            float ov[8];
            #pragma unroll
            for (int q = 0; q < 4; ++q) {
                float2 s0 = scsh[kk + 2 * q];
                float2 s1 = scsh[kk + 2 * q + 1];
                float x0 = s0.x * bf_lo(aa[q]) + s0.y;
                x0 = x0 > 0.f ? x0 : __expf(x0) - 1.f;
                x0 += bf_lo(rr[q]);
                float x1 = s1.x * bf_hi(aa[q]) + s1.y;
                x1 = x1 > 0.f ? x1 : __expf(x1) - 1.f;
                x1 += bf_hi(rr[q]);
                ov[2 * q] = x0; ov[2 * q + 1] = x1;
            }
            uint4 o;
            o.x = pack2(ov[0], ov[1]); o.y = pack2(ov[2], ov[3]);
            o.z = pack2(ov[4], ov[5]); o.w = pack2(ov[6], ov[7]);
            *(uint4*)(As + (size_t)idx * 8) = o;
            if (rowv[j] < NN) *(uint4*)(hbio + gi[j]) = o;   // new residual
        }
    }
    __syncthreads();                             // single staging barrier (drains DMA)

    float4v acc[2][4] = {};
    #pragma unroll
    for (int ks = 0; ks < 4; ++ks) {
        short8 a[2], b[4];
        #pragma unroll
        for (int tj = 0; tj < 4; ++tj)
            b[tj] = *(const short8*)(Bs + ((wn * 4 + tj) * 4 + ks) * 512 + lane * 8);
        #pragma unroll
        for (int ti = 0; ti < 2; ++ti)
            a[ti] = *(const short8*)(As + ((wm * 2 + ti) * 4 + ks) * 512 + lane * 8);
        #pragma unroll
        for (int ti = 0; ti < 2; ++ti)
            #pragma unroll
            for (int tj = 0; tj < 4; ++tj)
                acc[ti][tj] = __builtin_amdgcn_mfma_f32_16x16x32_bf16(
                    a[ti], b[tj], acc[ti][tj], 0, 0, 0);
    }
    __syncthreads();                             // protect LDS before sc overwrite

    float* sc = (float*)smem;
    for (int tp = 0; tp < 2; ++tp) {
        if ((wm >> 1) == tp) {
            #pragma unroll
            for (int ti = 0; ti < 2; ++ti) {
                #pragma unroll
                for (int tj = 0; tj < 4; ++tj) {
                    #pragma unroll
                    for (int r = 0; r < 4; ++r) {
                        int rloc = (wm & 1) * 32 + ti * 16 + quad * 4 + r;
                        int col = wn * 64 + tj * 16 + lr;
                        sc[rloc * 132 + col] = acc[ti][tj][r];
                    }
                }
            }
        }
        __syncthreads();
        #pragma unroll
        for (int j = 0; j < 4; ++j) {
            int idx = j * 512 + t;
            int row = idx >> 5;                 // [0,64)
            int c4 = (idx & 31) * 4;
            float4 v = *(const float4*)&sc[row * 132 + c4];
            int gr = row0 + tp * 64 + row;
            if (gr < NN) {
                uint2 u; u.x = pack2(v.x, v.y); u.y = pack2(v.z, v.w);
                *(uint2*)(Cb + (size_t)gr * 128 + c4) = u;
            }
        }
        {
            int row = t & 63, head = t >> 6;    // 512 tasks: 64 rows x 8 heads
            int gr = row0 + tp * 64 + row;
            if (gr < NN) {
                const float* rp = &sc[row * 132 + head * 16];
                const float* spv = a_src + head * 16;
                const float* dpv = a_dst + head * 16;
                float s1 = 0.f, s2 = 0.f;
                #pragma unroll
                for (int c = 0; c < 16; ++c) {
                    float hv = rp[c];
                    s1 += hv * spv[c];
                    s2 += hv * dpv[c];
                }
                al_s[gr * 8 + head] = s1 * LOG2E;
                al_d[gr * 8 + head] = s2 * LOG2E;
            }
        }
        __syncthreads();
    }
}

// ================= GAT aggregation + fused BN-stat partials ===================
// Round-3 gather core (measured best, product-limited ~3.6 TB/s). NEW: each
// block accumulates channel sum/sumsq of its 4 output nodes in LDS (fp32,
// pre-bf16-pack -> closer to reference than reading back bf16), then flushes
// 256 atomicAdds to srep[bid&63][256]. Grid is exactly NN/4 blocks (NN%4==0),
// so all threads reach the barriers (old wv>=NN early-return never fired).

__global__ __launch_bounds__(256) void gat_agg(
    const int* __restrict__ rowptr, const int* __restrict__ csrc,
    const uint4* __restrict__ h2b4, const float* __restrict__ al_s,
    const float* __restrict__ al_d, const float* __restrict__ bias,
    uint4* __restrict__ out4, float* __restrict__ srep)
{
    __shared__ float ssum[256];                  // [0,128) sum, [128,256) sumsq
    int tt = threadIdx.x;
    ssum[tt] = 0.f;
    __syncthreads();

    int wv = (blockIdx.x * blockDim.x + tt) >> 6;   // node id, always < NN
    int lane = tt & 63;
    int slot = lane >> 4;        // edge slot 0..3
    int ln = lane & 15;          // channels 8*ln .. 8*ln+7
    int head = ln >> 1;
    const char* hb8 = (const char*)h2b4;       // record = 256 B
    const char* as8 = (const char*)al_s;       // record = 32 B
    unsigned hoff = (unsigned)ln * 16u;
    unsigned aoff = (unsigned)head * 4u;
    int e0 = rowptr[wv], e1 = rowptr[wv + 1];
    float ald = al_d[(unsigned)wv * 8u + head];    // pre-scaled by log2e
    float ac[8] = {};
    float denom = 0.f;

    int e = e0;
    // 4-batch pipelined main loop: 16 edges per iteration
    for (; e + 16 <= e1; e += 16) {
        int sA = csrc[e + slot];
        int sB = csrc[e + 4 + slot];
        int sC = csrc[e + 8 + slot];
        int sD = csrc[e + 12 + slot];
        float aA = *(const float*)(as8 + ((unsigned)sA * 32u + aoff));
        float aB = *(const float*)(as8 + ((unsigned)sB * 32u + aoff));
        float aC = *(const float*)(as8 + ((unsigned)sC * 32u + aoff));
        float aD = *(const float*)(as8 + ((unsigned)sD * 32u + aoff));
        uint4 pA = *(const uint4*)(hb8 + ((unsigned)sA * 256u + hoff));
        uint4 pB = *(const uint4*)(hb8 + ((unsigned)sB * 256u + hoff));
        uint4 pC = *(const uint4*)(hb8 + ((unsigned)sC * 256u + hoff));
        uint4 pD = *(const uint4*)(hb8 + ((unsigned)sD * 256u + hoff));
        float xA = aA + ald; xA = fmaxf(xA, NEG_SLOPE * xA); float wA = exp2f(xA);
        float xB = aB + ald; xB = fmaxf(xB, NEG_SLOPE * xB); float wB = exp2f(xB);
        float xC = aC + ald; xC = fmaxf(xC, NEG_SLOPE * xC); float wC = exp2f(xC);
        float xD = aD + ald; xD = fmaxf(xD, NEG_SLOPE * xD); float wD = exp2f(xD);
        uint_t uA[4] = {pA.x, pA.y, pA.z, pA.w};
        uint_t uB[4] = {pB.x, pB.y, pB.z, pB.w};
        uint_t uC[4] = {pC.x, pC.y, pC.z, pC.w};
        uint_t uD[4] = {pD.x, pD.y, pD.z, pD.w};
        #pragma unroll
        for (int q = 0; q < 4; ++q) {
            ac[2 * q]     += wA * bf_lo(uA[q]) + wB * bf_lo(uB[q])
                           + wC * bf_lo(uC[q]) + wD * bf_lo(uD[q]);
            ac[2 * q + 1] += wA * bf_hi(uA[q]) + wB * bf_hi(uB[q])
                           + wC * bf_hi(uC[q]) + wD * bf_hi(uD[q]);
        }
        denom += (wA + wB) + (wC + wD);
    }
    // 2-batch: 8 edges per iteration
    for (; e + 8 <= e1; e += 8) {
        int sA = csrc[e + slot];
        int sB = csrc[e + 4 + slot];
        float aA = *(const float*)(as8 + ((unsigned)sA * 32u + aoff));
        float aB = *(const float*)(as8 + ((unsigned)sB * 32u + aoff));
        uint4 pA = *(const uint4*)(hb8 + ((unsigned)sA * 256u + hoff));
        uint4 pB = *(const uint4*)(hb8 + ((unsigned)sB * 256u + hoff));
        float xA = aA + ald; xA = fmaxf(xA, NEG_SLOPE * xA);
        float wA = exp2f(xA);
        float xB = aB + ald; xB = fmaxf(xB, NEG_SLOPE * xB);
        float wB = exp2f(xB);
        uint_t uA[4] = {pA.x, pA.y, pA.z, pA.w};
        uint_t uB[4] = {pB.x, pB.y, pB.z, pB.w};
        #pragma unroll
        for (int q = 0; q < 4; ++q) {
            ac[2 * q]     += wA * bf_lo(uA[q]) + wB * bf_lo(uB[q]);
            ac[2 * q + 1] += wA * bf_hi(uA[q]) + wB * bf_hi(uB[q]);
        }
        denom += wA + wB;
    }
    for (; e < e1; e += 4) {
        int idx = e + slot;
        bool valid = idx < e1;
        int s = csrc[valid ? idx : e];
        float a = *(const float*)(as8 + ((unsigned)s * 32u + aoff));
        uint4 p = *(const uint4*)(hb8 + ((unsigned)s * 256u + hoff));
        float x = a + ald; x = fmaxf(x, NEG_SLOPE * x);
        float w = valid ? exp2f(x) : 0.f;
        uint_t u[4] = {p.x, p.y, p.z, p.w};
        #pragma unroll
        for (int q = 0; q < 4; ++q) {
            ac[2 * q]     += w * bf_lo(u[q]);
            ac[2 * q + 1] += w * bf_hi(u[q]);
        }
        denom += w;
    }
    // combine the 4 edge slots (lanes differing in bits 4-5)
    #pragma unroll
    for (int q = 0; q < 8; ++q) {
        ac[q] += __shfl_xor(ac[q], 16, 64);
        ac[q] += __shfl_xor(ac[q], 32, 64);
    }
    denom += __shfl_xor(denom, 16, 64);
    denom += __shfl_xor(denom, 32, 64);
    if (slot == 0) {
        float inv = 1.0f / (denom + 1e-16f);
        int c = ln * 8;
        float4 b0 = *(const float4*)(bias + c);
        float4 b1 = *(const float4*)(bias + c + 4);
        float v0 = ac[0] * inv + b0.x, v1 = ac[1] * inv + b0.y;
        float v2 = ac[2] * inv + b0.z, v3 = ac[3] * inv + b0.w;
        float v4 = ac[4] * inv + b1.x, v5 = ac[5] * inv + b1.y;
        float v6 = ac[6] * inv + b1.z, v7 = ac[7] * inv + b1.w;
        uint4 o;
        o.x = pack2(v0, v1); o.y = pack2(v2, v3);
        o.z = pack2(v4, v5); o.w = pack2(v6, v7);
        out4[(size_t)wv * 16 + ln] = o;
        // BN-stat partials: 4 waves merge via LDS atomics (disjoint ch/wave)
        atomicAdd(&ssum[c + 0], v0);  atomicAdd(&ssum[128 + c + 0], v0 * v0);
        atomicAdd(&ssum[c + 1], v1);  atomicAdd(&ssum[128 + c + 1], v1 * v1);
        atomicAdd(&ssum[c + 2], v2);  atomicAdd(&ssum[128 + c + 2], v2 * v2);
        atomicAdd(&ssum[c + 3], v3);  atomicAdd(&ssum[128 + c + 3], v3 * v3);
        atomicAdd(&ssum[c + 4], v4);  atomicAdd(&ssum[128 + c + 4], v4 * v4);
        atomicAdd(&ssum[c + 5], v5);  atomicAdd(&ssum[128 + c + 5], v5 * v5);
        atomicAdd(&ssum[c + 6], v6);  atomicAdd(&ssum[128 + c + 6], v6 * v6);
        atomicAdd(&ssum[c + 7], v7);  atomicAdd(&ssum[128 + c + 7], v7 * v7);
    }
    __syncthreads();
    atomicAdd(&srep[(blockIdx.x & (SREP - 1)) * 256 + tt], ssum[tt]);
}

// ================= final FC (fused last BN+ELU+residual) =================

__global__ __launch_bounds__(256) void fc_fused(
    const uint_t* __restrict__ aggb, const uint_t* __restrict__ hb,
    const float* __restrict__ srep, const float* __restrict__ g,
    const float* __restrict__ be, const float* __restrict__ w,
    const float* __restrict__ fb, float* __restrict__ out)
{
    __shared__ float2 scsh[128];
    int t = threadIdx.x;
    if (t < 128) {
        float s_ = 0.f, q_ = 0.f;
        #pragma unroll 8
        for (int r = 0; r < SREP; ++r) {
            s_ += srep[r * 256 + t];
            q_ += srep[r * 256 + 128 + t];
        }
        float mu = s_ * (1.0f / NN);
        float var = q_ * (1.0f / NN) - mu * mu;
        float s = g[t] * rsqrtf(var + EPS_BN);
        scsh[t] = make_float2(s, be[t] - mu * s);
    }
    __syncthreads();
    int wv = (blockIdx.x * 256 + t) >> 6;
    int lane = t & 63;
    if (wv >= NN) return;
    uint_t av = aggb[(size_t)wv * 64 + lane];
    uint_t rv = hb[(size_t)wv * 64 + lane];
    int c = lane * 2;
    float2 s0 = scsh[c], s1 = scsh[c + 1];
    float x0 = s0.x * bf_lo(av) + s0.y;
    x0 = x0 > 0.f ? x0 : __expf(x0) - 1.f;
    x0 += bf_lo(rv);
    float x1 = s1.x * bf_hi(av) + s1.y;
    x1 = x1 > 0.f ? x1 : __expf(x1) - 1.f;
    x1 += bf_hi(rv);
    float2 wl = *(const float2*)(w + c);
    float acc = x0 * wl.x + x1 * wl.y;
    #pragma unroll
    for (int off = 32; off > 0; off >>= 1)
        acc += __shfl_down(acc, off, 64);
    if (lane == 0) out[wv] = acc + fb[0];
}

// ================= launch =================

extern "C" void kernel_launch(void* const* d_in, const int* in_sizes, int n_in,
                              void* d_out, int out_size, void* d_ws, size_t ws_size,
                              hipStream_t stream) {
    const float* x       = (const float*)d_in[0];
    const int*   ei      = (const int*)  d_in[1];
    const float* proj_w  = (const float*)d_in[2];
    const float* proj_b  = (const float*)d_in[3];
    const float* W       = (const float*)d_in[4];
    const float* att_src = (const float*)d_in[5];
    const float* att_dst = (const float*)d_in[6];
    const float* conv_b  = (const float*)d_in[7];
    const float* bn_g    = (const float*)d_in[8];
    const float* bn_b    = (const float*)d_in[9];
    const float* fc_w    = (const float*)d_in[10];
    const float* fc_b    = (const float*)d_in[11];
    float* out = (float*)d_out;

    char* p = (char*)d_ws;
    uint_t*   hb   = (uint_t*)p;   p += (size_t)NN * 64 * 4;         // 25.6 MB (bf16x2)
    uint_t*   h2b  = (uint_t*)p;   p += (size_t)NN * 64 * 4;         // 25.6 MB
    uint_t*   aggb = (uint_t*)p;   p += (size_t)NN * 64 * 4;         // 25.6 MB
    uint_t*   pairs = (uint_t*)aggb;                                  // alias (dead early)
    float*    al_s = (float*)p;    p += (size_t)NN * HEADS * 4;
    float*    al_d = (float*)p;    p += (size_t)NN * HEADS * 4;
    int* rowptr    = (int*)p;      p += ((size_t)(NN + 1) * 4 + 255) & ~255ull;
    int* csrc      = (int*)p;      p += (size_t)ETOT * 4;
    int* bcnt      = (int*)p;      p += 1024;                        // zeroed in castw
    float* srep3   = (float*)p;    p += 3 * SREP * 256 * 4;          // 192 KB, zeroed in castw
    int* bbase     = (int*)p;      p += 1024;
    int* lbase     = (int*)p;      p += (size_t)NBLK_A * NB * 4 + 256;
    ushort_t* pwT  = (ushort_t*)p; p += 128 * 256 * 2;
    ushort_t* WT   = (ushort_t*)p; p += 3 * 128 * 128 * 2;
    (void)ws_size; (void)n_in; (void)in_sizes; (void)out_size;

    // --- weights cast/transpose + zero bcnt/srep ---
    castw<<<320, 256, 0, stream>>>(proj_w, W, pwT, WT, bcnt, srep3);

    // --- initial projection: hb = bf16(elu(x @ proj_w + b)) ---
    proj_gemm<<<(NN + 127) / 128, 512, 0, stream>>>(x, pwT, proj_b, (ushort_t*)hb);

    // --- CSR build (bucketed counting sort); pairs alias aggb ---
    bucket_hist<<<NBLK_A, 256, 0, stream>>>(ei, bcnt, (int*)lbase);
    bucket_scan<<<1, 256, 0, stream>>>(bcnt, bbase, rowptr);
    bucket_scatter<<<NBLK_A, 256, 0, stream>>>(ei, bbase, (const int*)lbase, pairs);
    bucket_build<<<NB, 256, 0, stream>>>(pairs, bbase, rowptr, csrc);

    for (int l = 0; l < 3; ++l) {
        const ushort_t* WTl = WT + (size_t)l * 128 * 128;
        const float* asl = att_src + (size_t)l * HEADS * CH;
        const float* adl = att_dst + (size_t)l * HEADS * CH;
        const float* cbl = conv_b + (size_t)l * HID;
        float* srl = srep3 + (size_t)l * SREP * 256;

        if (l == 0) {
            layer_gemm<<<(NN + 127) / 128, 512, 0, stream>>>(
                hb, 0, WTl, (ushort_t*)h2b, asl, adl, al_s, al_d,
                nullptr, nullptr, nullptr, nullptr);
        } else {
            layer_gemm<<<(NN + 127) / 128, 512, 0, stream>>>(
                aggb, 2, WTl, (ushort_t*)h2b, asl, adl, al_s, al_d,
                hb, srep3 + (size_t)(l - 1) * SREP * 256,
                bn_g + (size_t)(l - 1) * HID, bn_b + (size_t)(l - 1) * HID);
        }
        gat_agg<<<NN / 4, 256, 0, stream>>>(
            rowptr, csrc, (const uint4*)h2b, al_s, al_d, cbl, (uint4*)aggb, srl);
    }

    // fc with fused layer-3 BN+ELU+residual (stats from srep layer 2)
    fc_fused<<<(NN + 3) / 4, 256, 0, stream>>>(
        aggb, hb, srep3 + 2 * (size_t)SREP * 256, bn_g + 2 * HID, bn_b + 2 * HID,
        fc_w, fc_b, out);
}

// Round 17
// 709.276 us; speedup vs baseline: 1.2517x; 1.2517x over previous
//
#include <hip/hip_runtime.h>
#include <hip/hip_bf16.h>

#define NN 100000
#define EE 1600000
#define ETOT (NN + EE)
#define HID 128
#define HEADS 8
#define CH 16
#define EPS_BN 1e-5f
#define NEG_SLOPE 0.2f
#define LOG2E 1.4426950408889634f
#define NB 196            // buckets of 512 dst nodes
#define NBLK_A 208        // ceil(ETOT / 8192)

typedef unsigned short ushort_t;
typedef unsigned int uint_t;
typedef __attribute__((ext_vector_type(8))) short short8;
typedef __attribute__((ext_vector_type(4))) float float4v;

__device__ inline uint_t f2bf(float x) {
    __hip_bfloat16 b = __float2bfloat16(x);
    return (uint_t)*reinterpret_cast<unsigned short*>(&b);
}
__device__ inline uint_t pack2(float lo, float hi) {
    return f2bf(lo) | (f2bf(hi) << 16);
}
__device__ inline float bf_lo(uint_t u) { return __uint_as_float(u << 16); }
__device__ inline float bf_hi(uint_t u) { return __uint_as_float(u & 0xffff0000u); }

// async global->LDS, 16B per lane; LDS dest must be wave-uniform base + lane*16
__device__ inline void gld_lds16(const void* g, void* l) {
    __builtin_amdgcn_global_load_lds(
        (const __attribute__((address_space(1))) unsigned int*)g,
        (__attribute__((address_space(3))) unsigned int*)l, 16, 0, 0);
}

// ================= CSR build: bucketed counting sort =================

__global__ __launch_bounds__(256) void bucket_hist(const int* __restrict__ ei,
                                                   int* bcnt, int* lbase) {
    __shared__ int h[256];
    int t = threadIdx.x;
    h[t] = 0;
    __syncthreads();
    int base = blockIdx.x * 8192;
    #pragma unroll 4
    for (int j = 0; j < 32; ++j) {
        int i = base + j * 256 + t;
        if (i < ETOT) {
            int d = (i < EE) ? ei[EE + i] : (i - EE);
            atomicAdd(&h[d >> 9], 1);
        }
    }
    __syncthreads();
    // guard t < NB: lbase stride is NB (round-4 crash root cause)
    if (t < NB) {
        int v = h[t];
        lbase[blockIdx.x * NB + t] = v ? atomicAdd(&bcnt[t], v) : 0;
    }
}

__global__ void bucket_scan(const int* __restrict__ bcnt, int* bbase, int* rowptr) {
    __shared__ int s[256];
    int t = threadIdx.x;
    int orig = (t < NB) ? bcnt[t] : 0;
    s[t] = orig;
    __syncthreads();
    for (int off = 1; off < 256; off <<= 1) {
        int add = (t >= off) ? s[t - off] : 0;
        __syncthreads();
        s[t] += add;
        __syncthreads();
    }
    if (t < NB) bbase[t] = s[t] - orig;
    if (t == 0) { bbase[NB] = ETOT; rowptr[NN] = ETOT; }
}

// LDS-staged counting sort per block; linear coalesced write.
__global__ __launch_bounds__(256) void bucket_scatter(const int* __restrict__ ei,
                                                      const int* __restrict__ bbase,
                                                      const int* __restrict__ lbase,
                                                      uint_t* __restrict__ pairs) {
    __shared__ uint_t spair[8192];
    __shared__ unsigned char sbk[8192];
    __shared__ int h[256];
    __shared__ int lscan[256];
    __shared__ int sbase[256];
    int t = threadIdx.x;
    int base = blockIdx.x * 8192;
    int nloc = ETOT - base; if (nloc > 8192) nloc = 8192;
    sbase[t] = (t < NB) ? (bbase[t] + lbase[blockIdx.x * NB + t]) : 0;
    h[t] = 0;
    __syncthreads();
    #pragma unroll 4
    for (int j = 0; j < 32; ++j) {
        int i = base + j * 256 + t;
        if (i < ETOT) {
            int d = (i < EE) ? ei[EE + i] : (i - EE);
            atomicAdd(&h[d >> 9], 1);
        }
    }
    __syncthreads();
    int orig = h[t];
    lscan[t] = orig;
    __syncthreads();
    for (int off = 1; off < 256; off <<= 1) {
        int add = (t >= off) ? lscan[t - off] : 0;
        __syncthreads();
        lscan[t] += add;
        __syncthreads();
    }
    int excl = lscan[t] - orig;
    __syncthreads();
    lscan[t] = excl;
    h[t] = excl;
    __syncthreads();
    #pragma unroll 4
    for (int j = 0; j < 32; ++j) {
        int i = base + j * 256 + t;
        if (i < ETOT) {
            int sv, dv;
            if (i < EE) { sv = ei[i]; dv = ei[EE + i]; }
            else        { sv = i - EE; dv = sv; }
            int bk = dv >> 9;
            int lp = atomicAdd(&h[bk], 1);
            spair[lp] = ((uint_t)sv << 9) | (uint_t)(dv & 511);
            sbk[lp] = (unsigned char)bk;
        }
    }
    __syncthreads();
    #pragma unroll 4
    for (int j = 0; j < 32; ++j) {
        int i = j * 256 + t;
        if (i < nloc) {
            int bk = sbk[i];
            pairs[sbase[bk] + (i - lscan[bk])] = spair[i];
        }
    }
}

__global__ __launch_bounds__(256) void bucket_build(const uint_t* __restrict__ pairs,
                                                    const int* __restrict__ bbase,
                                                    int* __restrict__ rowptr,
                                                    int* __restrict__ csrc) {
    __shared__ int cnt[512];
    __shared__ int cur[512];
    int b = blockIdx.x;
    int t = threadIdx.x;
    int lo = b << 9;
    int nn = NN - lo; if (nn > 512) nn = 512;
    int e0 = bbase[b];
    int e1 = bbase[b + 1];
    cnt[t] = 0; cnt[t + 256] = 0;
    __syncthreads();
    for (int i = e0 + t; i < e1; i += 256)
        atomicAdd(&cnt[pairs[i] & 511], 1);
    __syncthreads();
    int oc0 = cnt[t], oc1 = cnt[t + 256];
    for (int off = 1; off < 512; off <<= 1) {
        int i0 = t, i1 = t + 256;
        int a0 = cnt[i0] + ((i0 >= off) ? cnt[i0 - off] : 0);
        int a1 = cnt[i1] + ((i1 >= off) ? cnt[i1 - off] : 0);
        __syncthreads();
        cnt[i0] = a0; cnt[i1] = a1;
        __syncthreads();
    }
    int ex0 = cnt[t] - oc0, ex1 = cnt[t + 256] - oc1;
    __syncthreads();
    cur[t] = e0 + ex0; cur[t + 256] = e0 + ex1;
    if (t < nn)       rowptr[lo + t] = e0 + ex0;
    if (t + 256 < nn) rowptr[lo + 256 + t] = e0 + ex1;
    __syncthreads();
    for (int i = e0 + t; i < e1; i += 256) {
        uint_t p = pairs[i];
        int pos = atomicAdd(&cur[p & 511], 1);
        csrc[pos] = (int)(p >> 9);
    }
}

// ================= weight transpose + cast (+ zero bcnt/stats) =================

__global__ void castw(const float* __restrict__ proj_w, const float* __restrict__ W,
                      ushort_t* __restrict__ pwT, ushort_t* __restrict__ WT,
                      int* __restrict__ zbuf) {
    int id = blockIdx.x * 256 + threadIdx.x;
    if (id < 1024) zbuf[id] = 0;                           // bcnt + stats3 (4096 B)
    if (id < 32768) {
        int n = id >> 8, k = id & 255;
        pwT[id] = (ushort_t)f2bf(proj_w[k * 128 + n]);     // pwT[n][k], K=256
    } else if (id < 81920) {
        int id2 = id - 32768;
        int l = id2 >> 14, r = id2 & 16383;
        int n = r >> 7, k = r & 127;
        WT[id2] = (ushort_t)f2bf(W[l * 16384 + k * 128 + n]); // WT[l][n][k]
    }
}

// ================= proj GEMM (K=256, fp32 A): 512-thread frag-staged ==========
// (measured round 13: total 798.7 -> 774.4 with this kernel)

__global__ __launch_bounds__(512) void proj_gemm(
    const float* __restrict__ A, const ushort_t* __restrict__ Bt,
    const float* __restrict__ bias, ushort_t* __restrict__ Cb)
{
    __shared__ uint4 smem[4096];                 // 64 KB: A frags | B frags
    ushort_t* As = (ushort_t*)smem;              // 32 KB (one K=128 half)
    ushort_t* Bs = As + 16384;                   // 32 KB

    int t = threadIdx.x;
    int row0 = blockIdx.x * 128;
    int lane = t & 63, wv = t >> 6;              // 8 waves
    int wm = wv >> 1, wn = wv & 1;               // wm in [0,4), wn in [0,2)
    int lr = lane & 15, quad = lane >> 4;

    float4v acc[2][4] = {};

    for (int h = 0; h < 2; ++h) {
        #pragma unroll
        for (int j = 0; j < 4; ++j) {
            int idx = j * 512 + t;
            int tile = idx >> 8, ksf = (idx >> 6) & 3;
            int l = idx & 63;
            int n = tile * 16 + (l & 15);
            int kk = h * 128 + ksf * 32 + (l >> 4) * 8;
            gld_lds16(Bt + n * 256 + kk, Bs + (size_t)idx * 8);
        }
        #pragma unroll
        for (int j = 0; j < 4; ++j) {
            int idx = j * 512 + t;
            int tile = idx >> 8, ksf = (idx >> 6) & 3;
            int l = idx & 63;
            int row = row0 + tile * 16 + (l & 15);
            if (row >= NN) row = NN - 1;         // clamp: no OOB on input x
            int kk = h * 128 + ksf * 32 + (l >> 4) * 8;
            const float* src = A + (size_t)row * 256 + kk;
            float4 v0 = *(const float4*)(src);
            float4 v1 = *(const float4*)(src + 4);
            uint4 o;
            o.x = pack2(v0.x, v0.y); o.y = pack2(v0.z, v0.w);
            o.z = pack2(v1.x, v1.y); o.w = pack2(v1.z, v1.w);
            *(uint4*)(As + (size_t)idx * 8) = o;
        }
        __syncthreads();                         // drains DMA + ds_writes

        #pragma unroll
        for (int ks = 0; ks < 4; ++ks) {
            short8 a[2], b[4];
            #pragma unroll
            for (int tj = 0; tj < 4; ++tj)
                b[tj] = *(const short8*)(Bs + ((wn * 4 + tj) * 4 + ks) * 512 + lane * 8);
            #pragma unroll
            for (int ti = 0; ti < 2; ++ti)
                a[ti] = *(const short8*)(As + ((wm * 2 + ti) * 4 + ks) * 512 + lane * 8);
            #pragma unroll
            for (int ti = 0; ti < 2; ++ti)
                #pragma unroll
                for (int tj = 0; tj < 4; ++tj)
                    acc[ti][tj] = __builtin_amdgcn_mfma_f32_16x16x32_bf16(
                        a[ti], b[tj], acc[ti][tj], 0, 0, 0);
        }
        __syncthreads();                         // protect LDS before restage/bounce
    }

    float* sc = (float*)smem;
    for (int tp = 0; tp < 2; ++tp) {
        if ((wm >> 1) == tp) {
            #pragma unroll
            for (int ti = 0; ti < 2; ++ti) {
                #pragma unroll
                for (int tj = 0; tj < 4; ++tj) {
                    #pragma unroll
                    for (int r = 0; r < 4; ++r) {
                        int rloc = (wm & 1) * 32 + ti * 16 + quad * 4 + r;
                        int col = wn * 64 + tj * 16 + lr;
                        sc[rloc * 132 + col] = acc[ti][tj][r];
                    }
                }
            }
        }
        __syncthreads();
        #pragma unroll
        for (int j = 0; j < 4; ++j) {
            int idx = j * 512 + t;
            int row = idx >> 5;                 // [0,64)
            int c4 = (idx & 31) * 4;
            float4 v = *(const float4*)&sc[row * 132 + c4];
            int gr = row0 + tp * 64 + row;
            if (gr < NN) {
                float4 bv = *(const float4*)(bias + c4);
                v.x += bv.x; v.y += bv.y; v.z += bv.z; v.w += bv.w;
                v.x = v.x > 0.f ? v.x : __expf(v.x) - 1.f;
                v.y = v.y > 0.f ? v.y : __expf(v.y) - 1.f;
                v.z = v.z > 0.f ? v.z : __expf(v.z) - 1.f;
                v.w = v.w > 0.f ? v.w : __expf(v.w) - 1.f;
                uint2 u; u.x = pack2(v.x, v.y); u.y = pack2(v.z, v.w);
                *(uint2*)(Cb + (size_t)gr * 128 + c4) = u;
            }
        }
        __syncthreads();
    }
}

// ================= layer GEMM (K=128, N=128): 512-thread / 8-wave version =====

__global__ __launch_bounds__(512) void layer_gemm(
    const void* __restrict__ Aptr, int mode,
    const ushort_t* __restrict__ Bt, ushort_t* __restrict__ Cb,
    const float* __restrict__ a_src, const float* __restrict__ a_dst,
    float* __restrict__ al_s, float* __restrict__ al_d,
    uint_t* __restrict__ hbio, const float* __restrict__ stats,
    const float* __restrict__ bn_gl, const float* __restrict__ bn_bl)
{
    __shared__ uint4 smem[4096];                 // 64 KB: A frags | B frags
    __shared__ float2 scsh[128];
    ushort_t* As = (ushort_t*)smem;              // 2048 frags * 16 B
    ushort_t* Bs = As + 16384;

    int t = threadIdx.x;
    int row0 = blockIdx.x * 128;
    int lane = t & 63, wv = t >> 6;              // 8 waves
    int wm = wv >> 1, wn = wv & 1;               // wm in [0,4), wn in [0,2)
    int lr = lane & 15, quad = lane >> 4;

    if (mode == 2) {
        if (t < 128) {
            float mu = stats[t] * (1.0f / NN);
            float var = stats[128 + t] * (1.0f / NN) - mu * mu;
            float s = bn_gl[t] * rsqrtf(var + EPS_BN);
            scsh[t] = make_float2(s, bn_bl[t] - mu * s);
        }
        __syncthreads();                         // scsh visible before transforms
    }

    #pragma unroll
    for (int j = 0; j < 4; ++j) {
        int idx = j * 512 + t;
        int tile = idx >> 8, ksf = (idx >> 6) & 3;
        int l = idx & 63;
        int n = tile * 16 + (l & 15);
        int kk = ksf * 32 + (l >> 4) * 8;
        gld_lds16(Bt + n * 128 + kk, Bs + (size_t)idx * 8);
    }

    if (mode == 0) {
        const ushort_t* A = (const ushort_t*)Aptr;
        #pragma unroll
        for (int j = 0; j < 4; ++j) {
            int idx = j * 512 + t;
            int tile = idx >> 8, ksf = (idx >> 6) & 3;
            int l = idx & 63;
            int row = row0 + tile * 16 + (l & 15);   // OOB rows read garbage -> dead C rows only
            int kk = ksf * 32 + (l >> 4) * 8;
            gld_lds16(A + (size_t)row * 128 + kk, As + (size_t)idx * 8);
        }
    } else {
        const uint_t* agg = (const uint_t*)Aptr;
        uint4 av[4], rv[4];
        unsigned gi[4];
        int rowv[4];
        #pragma unroll
        for (int j = 0; j < 4; ++j) {
            int idx = j * 512 + t;
            int tile = idx >> 8;
            int ksf = (idx >> 6) & 3;
            int l = idx & 63;
            int row = row0 + tile * 16 + (l & 15);
            int kk = ksf * 32 + (l >> 4) * 8;
            unsigned ui = (unsigned)row * 64u + (unsigned)(kk >> 1);
            gi[j] = ui; rowv[j] = row;
            av[j] = *(const uint4*)(agg + ui);
            rv[j] = *(const uint4*)(hbio + ui);
        }
        #pragma unroll
        for (int j = 0; j < 4; ++j) {
            int idx = j * 512 + t;
            int ksf = (idx >> 6) & 3;
            int l = idx & 63;
            int kk = ksf * 32 + (l >> 4) * 8;        // channel base, 8 channels
            uint_t aa[4] = {av[j].x, av[j].y, av[j].z, av[j].w};
            uint_t rr[4] = {rv[j].x, rv[j].y, rv[j].z, rv[j].w};
            float ov[8];
            #pragma unroll
            for (int q = 0; q < 4; ++q) {
                float2 s0 = scsh[kk + 2 * q];
                float2 s1 = scsh[kk + 2 * q + 1];
                float x0 = s0.x * bf_lo(aa[q]) + s0.y;
                x0 = x0 > 0.f ? x0 : __expf(x0) - 1.f;
                x0 += bf_lo(rr[q]);
                float x1 = s1.x * bf_hi(aa[q]) + s1.y;
                x1 = x1 > 0.f ? x1 : __expf(x1) - 1.f;
                x1 += bf_hi(rr[q]);
                ov[2 * q] = x0; ov[2 * q + 1] = x1;
            }
            uint4 o;
            o.x = pack2(ov[0], ov[1]); o.y = pack2(ov[2], ov[3]);
            o.z = pack2(ov[4], ov[5]); o.w = pack2(ov[6], ov[7]);
            *(uint4*)(As + (size_t)idx * 8) = o;
            if (rowv[j] < NN) *(uint4*)(hbio + gi[j]) = o;   // new residual
        }
    }
    __syncthreads();                             // single staging barrier (drains DMA)

    float4v acc[2][4] = {};
    #pragma unroll
    for (int ks = 0; ks < 4; ++ks) {
        short8 a[2], b[4];
        #pragma unroll
        for (int tj = 0; tj < 4; ++tj)
            b[tj] = *(const short8*)(Bs + ((wn * 4 + tj) * 4 + ks) * 512 + lane * 8);
        #pragma unroll
        for (int ti = 0; ti < 2; ++ti)
            a[ti] = *(const short8*)(As + ((wm * 2 + ti) * 4 + ks) * 512 + lane * 8);
        #pragma unroll
        for (int ti = 0; ti < 2; ++ti)
            #pragma unroll
            for (int tj = 0; tj < 4; ++tj)
                acc[ti][tj] = __builtin_amdgcn_mfma_f32_16x16x32_bf16(
                    a[ti], b[tj], acc[ti][tj], 0, 0, 0);
    }
    __syncthreads();                             // protect LDS before sc overwrite

    float* sc = (float*)smem;
    for (int tp = 0; tp < 2; ++tp) {
        if ((wm >> 1) == tp) {
            #pragma unroll
            for (int ti = 0; ti < 2; ++ti) {
                #pragma unroll
                for (int tj = 0; tj < 4; ++tj) {
                    #pragma unroll
                    for (int r = 0; r < 4; ++r) {
                        int rloc = (wm & 1) * 32 + ti * 16 + quad * 4 + r;
                        int col = wn * 64 + tj * 16 + lr;
                        sc[rloc * 132 + col] = acc[ti][tj][r];
                    }
                }
            }
        }
        __syncthreads();
        #pragma unroll
        for (int j = 0; j < 4; ++j) {
            int idx = j * 512 + t;
            int row = idx >> 5;                 // [0,64)
            int c4 = (idx & 31) * 4;
            float4 v = *(const float4*)&sc[row * 132 + c4];
            int gr = row0 + tp * 64 + row;
            if (gr < NN) {
                uint2 u; u.x = pack2(v.x, v.y); u.y = pack2(v.z, v.w);
                *(uint2*)(Cb + (size_t)gr * 128 + c4) = u;
            }
        }
        {
            int row = t & 63, head = t >> 6;    // 512 tasks: 64 rows x 8 heads
            int gr = row0 + tp * 64 + row;
            if (gr < NN) {
                const float* rp = &sc[row * 132 + head * 16];
                const float* spv = a_src + head * 16;
                const float* dpv = a_dst + head * 16;
                float s1 = 0.f, s2 = 0.f;
                #pragma unroll
                for (int c = 0; c < 16; ++c) {
                    float hv = rp[c];
                    s1 += hv * spv[c];
                    s2 += hv * dpv[c];
                }
                al_s[gr * 8 + head] = s1 * LOG2E;
                al_d[gr * 8 + head] = s2 * LOG2E;
            }
        }
        __syncthreads();
    }
}

// ================= GAT aggregation (round-3 variant: best measured, 80.6us) ===
// Round-15 lesson: fusing BN-stat global atomics here costs +89us/dispatch
// (6.4M atomics halve memory throughput). Keep pure; bn_stats is separate.

__global__ __launch_bounds__(256) void gat_agg(
    const int* __restrict__ rowptr, const int* __restrict__ csrc,
    const uint4* __restrict__ h2b4, const float* __restrict__ al_s,
    const float* __restrict__ al_d, const float* __restrict__ bias,
    uint4* __restrict__ out4)
{
    int wv = (blockIdx.x * blockDim.x + threadIdx.x) >> 6;
    int lane = threadIdx.x & 63;
    if (wv >= NN) return;
    int slot = lane >> 4;        // edge slot 0..3
    int ln = lane & 15;          // channels 8*ln .. 8*ln+7
    int head = ln >> 1;
    const char* hb8 = (const char*)h2b4;       // record = 256 B
    const char* as8 = (const char*)al_s;       // record = 32 B
    unsigned hoff = (unsigned)ln * 16u;
    unsigned aoff = (unsigned)head * 4u;
    int e0 = rowptr[wv], e1 = rowptr[wv + 1];
    float ald = al_d[(unsigned)wv * 8u + head];    // pre-scaled by log2e
    float ac[8] = {};
    float denom = 0.f;

    int e = e0;
    // 4-batch pipelined main loop: 16 edges per iteration
    for (; e + 16 <= e1; e += 16) {
        int sA = csrc[e + slot];
        int sB = csrc[e + 4 + slot];
        int sC = csrc[e + 8 + slot];
        int sD = csrc[e + 12 + slot];
        float aA = *(const float*)(as8 + ((unsigned)sA * 32u + aoff));
        float aB = *(const float*)(as8 + ((unsigned)sB * 32u + aoff));
        float aC = *(const float*)(as8 + ((unsigned)sC * 32u + aoff));
        float aD = *(const float*)(as8 + ((unsigned)sD * 32u + aoff));
        uint4 pA = *(const uint4*)(hb8 + ((unsigned)sA * 256u + hoff));
        uint4 pB = *(const uint4*)(hb8 + ((unsigned)sB * 256u + hoff));
        uint4 pC = *(const uint4*)(hb8 + ((unsigned)sC * 256u + hoff));
        uint4 pD = *(const uint4*)(hb8 + ((unsigned)sD * 256u + hoff));
        float xA = aA + ald; xA = fmaxf(xA, NEG_SLOPE * xA); float wA = exp2f(xA);
        float xB = aB + ald; xB = fmaxf(xB, NEG_SLOPE * xB); float wB = exp2f(xB);
        float xC = aC + ald; xC = fmaxf(xC, NEG_SLOPE * xC); float wC = exp2f(xC);
        float xD = aD + ald; xD = fmaxf(xD, NEG_SLOPE * xD); float wD = exp2f(xD);
        uint_t uA[4] = {pA.x, pA.y, pA.z, pA.w};
        uint_t uB[4] = {pB.x, pB.y, pB.z, pB.w};
        uint_t uC[4] = {pC.x, pC.y, pC.z, pC.w};
        uint_t uD[4] = {pD.x, pD.y, pD.z, pD.w};
        #pragma unroll
        for (int q = 0; q < 4; ++q) {
            ac[2 * q]     += wA * bf_lo(uA[q]) + wB * bf_lo(uB[q])
                           + wC * bf_lo(uC[q]) + wD * bf_lo(uD[q]);
            ac[2 * q + 1] += wA * bf_hi(uA[q]) + wB * bf_hi(uB[q])
                           + wC * bf_hi(uC[q]) + wD * bf_hi(uD[q]);
        }
        denom += (wA + wB) + (wC + wD);
    }
    // 2-batch: 8 edges per iteration
    for (; e + 8 <= e1; e += 8) {
        int sA = csrc[e + slot];
        int sB = csrc[e + 4 + slot];
        float aA = *(const float*)(as8 + ((unsigned)sA * 32u + aoff));
        float aB = *(const float*)(as8 + ((unsigned)sB * 32u + aoff));
        uint4 pA = *(const uint4*)(hb8 + ((unsigned)sA * 256u + hoff));
        uint4 pB = *(const uint4*)(hb8 + ((unsigned)sB * 256u + hoff));
        float xA = aA + ald; xA = fmaxf(xA, NEG_SLOPE * xA);
        float wA = exp2f(xA);
        float xB = aB + ald; xB = fmaxf(xB, NEG_SLOPE * xB);
        float wB = exp2f(xB);
        uint_t uA[4] = {pA.x, pA.y, pA.z, pA.w};
        uint_t uB[4] = {pB.x, pB.y, pB.z, pB.w};
        #pragma unroll
        for (int q = 0; q < 4; ++q) {
            ac[2 * q]     += wA * bf_lo(uA[q]) + wB * bf_lo(uB[q]);
            ac[2 * q + 1] += wA * bf_hi(uA[q]) + wB * bf_hi(uB[q]);
        }
        denom += wA + wB;
    }
    for (; e < e1; e += 4) {
        int idx = e + slot;
        bool valid = idx < e1;
        int s = csrc[valid ? idx : e];
        float a = *(const float*)(as8 + ((unsigned)s * 32u + aoff));
        uint4 p = *(const uint4*)(hb8 + ((unsigned)s * 256u + hoff));
        float x = a + ald; x = fmaxf(x, NEG_SLOPE * x);
        float w = valid ? exp2f(x) : 0.f;
        uint_t u[4] = {p.x, p.y, p.z, p.w};
        #pragma unroll
        for (int q = 0; q < 4; ++q) {
            ac[2 * q]     += w * bf_lo(u[q]);
            ac[2 * q + 1] += w * bf_hi(u[q]);
        }
        denom += w;
    }
    // combine the 4 edge slots (lanes differing in bits 4-5)
    #pragma unroll
    for (int q = 0; q < 8; ++q) {
        ac[q] += __shfl_xor(ac[q], 16, 64);
        ac[q] += __shfl_xor(ac[q], 32, 64);
    }
    denom += __shfl_xor(denom, 16, 64);
    denom += __shfl_xor(denom, 32, 64);
    if (slot == 0) {
        float inv = 1.0f / (denom + 1e-16f);
        int c = ln * 8;
        float4 b0 = *(const float4*)(bias + c);
        float4 b1 = *(const float4*)(bias + c + 4);
        uint4 o;
        o.x = pack2(ac[0] * inv + b0.x, ac[1] * inv + b0.y);
        o.y = pack2(ac[2] * inv + b0.z, ac[3] * inv + b0.w);
        o.z = pack2(ac[4] * inv + b1.x, ac[5] * inv + b1.y);
        o.w = pack2(ac[6] * inv + b1.z, ac[7] * inv + b1.w);
        out4[(size_t)wv * 16 + ln] = o;
    }
}

// ================= batchnorm stats (vectorized: 256B/wave coalesced) ==========
// 256 threads = 64 u32-cols x 4 row-groups; each wave reads a full 256B row
// segment once (old version: 128B/wave, every u32 fetched twice). LDS-reduce
// across groups, 256 atomics/block to stats (131K total -- known-fine volume).

__global__ __launch_bounds__(256) void bn_stats(const uint_t* __restrict__ ab,
                                                float* __restrict__ stats) {
    __shared__ float red[1024];                  // [grp][col][s0,s1,q0,q1]
    int t = threadIdx.x;
    int col = t & 63, grp = t >> 6;
    float s0 = 0.f, s1 = 0.f, q0 = 0.f, q1 = 0.f;
    for (int r = blockIdx.x * 4 + grp; r < NN; r += gridDim.x * 4) {
        uint_t u = ab[(size_t)r * 64 + col];
        float lo = bf_lo(u), hi = bf_hi(u);
        s0 += lo; q0 += lo * lo;
        s1 += hi; q1 += hi * hi;
    }
    red[grp * 256 + col * 4 + 0] = s0;
    red[grp * 256 + col * 4 + 1] = s1;
    red[grp * 256 + col * 4 + 2] = q0;
    red[grp * 256 + col * 4 + 3] = q1;
    __syncthreads();
    if (t < 64) {
        float a0 = 0.f, a1 = 0.f, b0 = 0.f, b1 = 0.f;
        #pragma unroll
        for (int g = 0; g < 4; ++g) {
            a0 += red[g * 256 + t * 4 + 0];
            a1 += red[g * 256 + t * 4 + 1];
            b0 += red[g * 256 + t * 4 + 2];
            b1 += red[g * 256 + t * 4 + 3];
        }
        atomicAdd(&stats[2 * t], a0);
        atomicAdd(&stats[2 * t + 1], a1);
        atomicAdd(&stats[HID + 2 * t], b0);
        atomicAdd(&stats[HID + 2 * t + 1], b1);
    }
}

// ================= final FC (fused last BN+ELU+residual) =================

__global__ __launch_bounds__(256) void fc_fused(
    const uint_t* __restrict__ aggb, const uint_t* __restrict__ hb,
    const float* __restrict__ stats, const float* __restrict__ g,
    const float* __restrict__ be, const float* __restrict__ w,
    const float* __restrict__ fb, float* __restrict__ out)
{
    __shared__ float2 scsh[128];
    int t = threadIdx.x;
    if (t < 128) {
        float mu = stats[t] * (1.0f / NN);
        float var = stats[128 + t] * (1.0f / NN) - mu * mu;
        float s = g[t] * rsqrtf(var + EPS_BN);
        scsh[t] = make_float2(s, be[t] - mu * s);
    }
    __syncthreads();
    int wv = (blockIdx.x * 256 + t) >> 6;
    int lane = t & 63;
    if (wv >= NN) return;
    uint_t av = aggb[(size_t)wv * 64 + lane];
    uint_t rv = hb[(size_t)wv * 64 + lane];
    int c = lane * 2;
    float2 s0 = scsh[c], s1 = scsh[c + 1];
    float x0 = s0.x * bf_lo(av) + s0.y;
    x0 = x0 > 0.f ? x0 : __expf(x0) - 1.f;
    x0 += bf_lo(rv);
    float x1 = s1.x * bf_hi(av) + s1.y;
    x1 = x1 > 0.f ? x1 : __expf(x1) - 1.f;
    x1 += bf_hi(rv);
    float2 wl = *(const float2*)(w + c);
    float acc = x0 * wl.x + x1 * wl.y;
    #pragma unroll
    for (int off = 32; off > 0; off >>= 1)
        acc += __shfl_down(acc, off, 64);
    if (lane == 0) out[wv] = acc + fb[0];
}

// ================= launch =================

extern "C" void kernel_launch(void* const* d_in, const int* in_sizes, int n_in,
                              void* d_out, int out_size, void* d_ws, size_t ws_size,
                              hipStream_t stream) {
    const float* x       = (const float*)d_in[0];
    const int*   ei      = (const int*)  d_in[1];
    const float* proj_w  = (const float*)d_in[2];
    const float* proj_b  = (const float*)d_in[3];
    const float* W       = (const float*)d_in[4];
    const float* att_src = (const float*)d_in[5];
    const float* att_dst = (const float*)d_in[6];
    const float* conv_b  = (const float*)d_in[7];
    const float* bn_g    = (const float*)d_in[8];
    const float* bn_b    = (const float*)d_in[9];
    const float* fc_w    = (const float*)d_in[10];
    const float* fc_b    = (const float*)d_in[11];
    float* out = (float*)d_out;

    char* p = (char*)d_ws;
    uint_t*   hb   = (uint_t*)p;   p += (size_t)NN * 64 * 4;         // 25.6 MB (bf16x2)
    uint_t*   h2b  = (uint_t*)p;   p += (size_t)NN * 64 * 4;         // 25.6 MB
    uint_t*   aggb = (uint_t*)p;   p += (size_t)NN * 64 * 4;         // 25.6 MB
    uint_t*   pairs = (uint_t*)aggb;                                  // alias (dead early)
    float*    al_s = (float*)p;    p += (size_t)NN * HEADS * 4;
    float*    al_d = (float*)p;    p += (size_t)NN * HEADS * 4;
    int* rowptr    = (int*)p;      p += ((size_t)(NN + 1) * 4 + 255) & ~255ull;
    int* csrc      = (int*)p;      p += (size_t)ETOT * 4;
    int* bcnt      = (int*)p;      p += 1024;                        // zeroed in castw
    float* stats3  = (float*)p;    p += 3 * 1024;                    // zeroed in castw
    int* bbase     = (int*)p;      p += 1024;
    int* lbase     = (int*)p;      p += (size_t)NBLK_A * NB * 4 + 256;
    ushort_t* pwT  = (ushort_t*)p; p += 128 * 256 * 2;
    ushort_t* WT   = (ushort_t*)p; p += 3 * 128 * 128 * 2;
    (void)ws_size; (void)n_in; (void)in_sizes; (void)out_size;

    // --- weights cast/transpose + zero bcnt/stats3 ---
    castw<<<320, 256, 0, stream>>>(proj_w, W, pwT, WT, bcnt);

    // --- initial projection: hb = bf16(elu(x @ proj_w + b)) ---
    proj_gemm<<<(NN + 127) / 128, 512, 0, stream>>>(x, pwT, proj_b, (ushort_t*)hb);

    // --- CSR build (bucketed counting sort); pairs alias aggb ---
    bucket_hist<<<NBLK_A, 256, 0, stream>>>(ei, bcnt, (int*)lbase);
    bucket_scan<<<1, 256, 0, stream>>>(bcnt, bbase, rowptr);
    bucket_scatter<<<NBLK_A, 256, 0, stream>>>(ei, bbase, (const int*)lbase, pairs);
    bucket_build<<<NB, 256, 0, stream>>>(pairs, bbase, rowptr, csrc);

    for (int l = 0; l < 3; ++l) {
        const ushort_t* WTl = WT + (size_t)l * 128 * 128;
        const float* asl = att_src + (size_t)l * HEADS * CH;
        const float* adl = att_dst + (size_t)l * HEADS * CH;
        const float* cbl = conv_b + (size_t)l * HID;
        float* stl = stats3 + l * 256;

        if (l == 0) {
            layer_gemm<<<(NN + 127) / 128, 512, 0, stream>>>(
                hb, 0, WTl, (ushort_t*)h2b, asl, adl, al_s, al_d,
                nullptr, nullptr, nullptr, nullptr);
        } else {
            layer_gemm<<<(NN + 127) / 128, 512, 0, stream>>>(
                aggb, 2, WTl, (ushort_t*)h2b, asl, adl, al_s, al_d,
                hb, stats3 + (l - 1) * 256, bn_g + (size_t)(l - 1) * HID,
                bn_b + (size_t)(l - 1) * HID);
        }
        gat_agg<<<(NN + 3) / 4, 256, 0, stream>>>(
            rowptr, csrc, (const uint4*)h2b, al_s, al_d, cbl, (uint4*)aggb);
        bn_stats<<<512, 256, 0, stream>>>(aggb, stl);
    }

    // fc with fused layer-3 BN+ELU+residual
    fc_fused<<<(NN + 3) / 4, 256, 0, stream>>>(
        aggb, hb, stats3 + 2 * 256, bn_g + 2 * HID, bn_b + 2 * HID, fc_w, fc_b, out);
}